// Round 15
// baseline (1615.064 us; speedup 1.0000x reference)
//
#include <hip/hip_runtime.h>

#define NB 32
#define LL 2048
#define DD 1024      // D2
#define AA 512       // ATTN
#define TT 8
#define LOG2E 1.4426950408889634f

typedef short short8 __attribute__((ext_vector_type(8)));
typedef float f32x4 __attribute__((ext_vector_type(4)));

#if __has_builtin(__builtin_amdgcn_exp2f)
#define EXP2(x) __builtin_amdgcn_exp2f(x)
#else
#define EXP2(x) exp2f(x)
#endif
#if __has_builtin(__builtin_amdgcn_rcpf)
#define RCP(x) __builtin_amdgcn_rcpf(x)
#else
#define RCP(x) (1.0f/(x))
#endif

__device__ __forceinline__ unsigned short f2b(float f){
  union { float f; unsigned u; } v; v.f = f;
  unsigned r = v.u + 0x7fffu + ((v.u >> 16) & 1u);
  return (unsigned short)(r >> 16);
}
__device__ __forceinline__ float b2f(unsigned short b){
  union { unsigned u; float f; } v; v.u = ((unsigned)b) << 16;
  return v.f;
}
__device__ __forceinline__ float sigm(float x){
  return RCP(1.f + EXP2(-x * LOG2E));
}
__device__ __forceinline__ float tanh_f(float x){
  return 2.f * RCP(1.f + EXP2(-2.f * LOG2E * x)) - 1.f;
}
__device__ __forceinline__ void gll16(const void* g, void* l){
  __builtin_amdgcn_global_load_lds(
      (const __attribute__((address_space(1))) unsigned int*)(g),
      (__attribute__((address_space(3))) unsigned int*)(l),
      16, 0, 0);
}

// ---- fp8 e4m3 (OCP) encode/decode, HW builtin with SW fallback ----
__device__ __forceinline__ unsigned char sw_enc_e4m3(float f){
  union{float f;unsigned u;} v; v.f = f;
  unsigned s = (v.u>>31)<<7;
  float a = fabsf(f);
  if (a < 0.015625f){
    int q = (int)(a*512.f + 0.5f);
    if (q > 7) return s | (1<<3);
    return s | q;
  }
  int e = ((v.u>>23)&255) - 127;
  unsigned m = ((v.u & 0x7FFFFF) + 0x80000) >> 20;
  if (m == 8){ m = 0; e++; }
  int eb = e + 7;
  if (eb > 15){ eb = 15; m = 6; }
  if (eb <= 0){
    int q = (int)(a*512.f + 0.5f); if (q>7) q=7;
    return s | q;
  }
  return s | (eb<<3) | m;
}
__device__ __forceinline__ unsigned char f2e8(float f){
#if __has_builtin(__builtin_amdgcn_cvt_pk_fp8_f32)
  return (unsigned char)(__builtin_amdgcn_cvt_pk_fp8_f32(f, f, 0, false) & 0xFF);
#else
  return sw_enc_e4m3(f);
#endif
}
__device__ __forceinline__ float sw_dec_e4m3(unsigned char c){
  unsigned s = c>>7, e = (c>>3)&15, m = c&7;
  if (e){ union{unsigned u;float f;} x; x.u = (s<<31)|((e+120)<<23)|(m<<20); return x.f; }
  float r = (float)m * 0.001953125f;
  return s ? -r : r;
}
#if __has_builtin(__builtin_amdgcn_cvt_f32_fp8)
#define DEC8(word, sel) __builtin_amdgcn_cvt_f32_fp8((int)(word), (sel))
#else
#define DEC8(word, sel) sw_dec_e4m3((unsigned char)(((word) >> ((sel)*8)) & 0xFF))
#endif

// ---------------- enc cvt: fp32 -> fp8 only ----------------
__global__ __launch_bounds__(256) void k_cvt_enc(const float* __restrict__ in,
                                                 unsigned char* __restrict__ o8,
                                                 long n8){
  long stride = (long)gridDim.x * 256;
  for (long i = (long)blockIdx.x*256 + threadIdx.x; i < n8; i += stride){
    const float4* ip = (const float4*)(in + i*8);
    float4 a = ip[0], b = ip[1];
    uint2 p;
    p.x = (unsigned)f2e8(a.x) | ((unsigned)f2e8(a.y)<<8) |
          ((unsigned)f2e8(a.z)<<16) | ((unsigned)f2e8(a.w)<<24);
    p.y = (unsigned)f2e8(b.x) | ((unsigned)f2e8(b.y)<<8) |
          ((unsigned)f2e8(b.z)<<16) | ((unsigned)f2e8(b.w)<<24);
    *(uint2*)(o8 + i*8) = p;
  }
}

// ---------------- weight cvts: Wih/Whh/W1 -> bf16, W2 -> fp8 x32 ----------
__global__ __launch_bounds__(256) void k_cvt4(
    const float* __restrict__ s0, const float* __restrict__ s1,
    const float* __restrict__ s2, const float* __restrict__ s3,
    unsigned short* __restrict__ d0, unsigned short* __restrict__ d1,
    unsigned short* __restrict__ d2, unsigned char* __restrict__ d3,
    long c0, long c1, long c2, long c3)
{
  long i = (long)blockIdx.x*256 + threadIdx.x;
  long idx = i;
  const float* s; unsigned short* d;
  if (idx < c0){ s = s0; d = d0; }
  else { idx -= c0;
    if (idx < c1){ s = s1; d = d1; }
    else { idx -= c1;
      if (idx < c2){ s = s2; d = d2; }
      else {
        idx -= c2; if (idx >= c3) return;
        const float4* ip = (const float4*)(s3 + idx*8);
        float4 a = ip[0], b = ip[1];
        uint2 p;
        p.x = (unsigned)f2e8(a.x*32.f) | ((unsigned)f2e8(a.y*32.f)<<8) |
              ((unsigned)f2e8(a.z*32.f)<<16) | ((unsigned)f2e8(a.w*32.f)<<24);
        p.y = (unsigned)f2e8(b.x*32.f) | ((unsigned)f2e8(b.y*32.f)<<8) |
              ((unsigned)f2e8(b.z*32.f)<<16) | ((unsigned)f2e8(b.w*32.f)<<24);
        *(uint2*)(d3 + idx*8) = p;
        return;
      } } }
  const float4* ip = (const float4*)(s + idx*8);
  float4 a = ip[0], b = ip[1];
  uint4 o;
  o.x = (unsigned)f2b(a.x) | ((unsigned)f2b(a.y) << 16);
  o.y = (unsigned)f2b(a.z) | ((unsigned)f2b(a.w) << 16);
  o.z = (unsigned)f2b(b.x) | ((unsigned)f2b(b.y) << 16);
  o.w = (unsigned)f2b(b.z) | ((unsigned)f2b(b.w) << 16);
  *(uint4*)(d + idx*8) = o;
}

// ---------------- enc_proj GEMM, fp8 x fp8 (W2 pre-scaled x32) ------------
__global__ __launch_bounds__(256) void k_gemm8(
    const unsigned char* __restrict__ A,   // [65536,1024] fp8 enc
    const unsigned char* __restrict__ Bt,  // [512,1024] fp8 (W2*32)
    const float* __restrict__ b2,
    unsigned char* __restrict__ C8)        // [65536,512] fp8 ep
{
  __shared__ unsigned char As[128*64];
  __shared__ unsigned char Bs[128*64];
  const int tid = threadIdx.x;
  const int wid = tid >> 6, lane = tid & 63;
  const int wm = wid >> 1, wn = wid & 1;
  const int hi = lane >> 4, r = lane & 15;
  const long brow = (long)blockIdx.x * 128;
  const int bcol = blockIdx.y * 128;
  const int srow = wid*32 + (lane >> 2);
  const int scol = (lane & 3) * 16;
  const unsigned char* aS0 = A + (brow + srow)*1024 + scol;
  const unsigned char* aS1 = A + (brow + srow + 16)*1024 + scol;
  const unsigned char* bS0 = Bt + (long)(bcol + srow)*1024 + scol;
  const unsigned char* bS1 = Bt + (long)(bcol + srow + 16)*1024 + scol;
  char* aD = (char*)As + wid*2048;
  char* bD = (char*)Bs + wid*2048;

  f32x4 acc[4][4];
  #pragma unroll
  for (int i=0;i<4;i++)
    #pragma unroll
    for (int j=0;j<4;j++) acc[i][j] = (f32x4){0.f,0.f,0.f,0.f};

  for (int k0 = 0; k0 < 1024; k0 += 64){
    __syncthreads();
    gll16(aS0 + k0, aD);
    gll16(aS1 + k0, aD + 1024);
    gll16(bS0 + k0, bD);
    gll16(bS1 + k0, bD + 1024);
    __syncthreads();
    long af[4][2], bfr[4][2];
    #pragma unroll
    for (int fm=0; fm<4; fm++){
      af[fm][0] = *(const long*)((const char*)As + (wm*64 + fm*16 + r)*64 + hi*8);
      af[fm][1] = *(const long*)((const char*)As + (wm*64 + fm*16 + r)*64 + 32 + hi*8);
    }
    #pragma unroll
    for (int fn=0; fn<4; fn++){
      bfr[fn][0] = *(const long*)((const char*)Bs + (wn*64 + fn*16 + r)*64 + hi*8);
      bfr[fn][1] = *(const long*)((const char*)Bs + (wn*64 + fn*16 + r)*64 + 32 + hi*8);
    }
    #pragma unroll
    for (int fm=0; fm<4; fm++)
      #pragma unroll
      for (int fn=0; fn<4; fn++){
        acc[fm][fn] = __builtin_amdgcn_mfma_f32_16x16x32_fp8_fp8(af[fm][0], bfr[fn][0], acc[fm][fn], 0, 0, 0);
        acc[fm][fn] = __builtin_amdgcn_mfma_f32_16x16x32_fp8_fp8(af[fm][1], bfr[fn][1], acc[fm][fn], 0, 0, 0);
      }
  }
  const float inv32 = 1.f/32.f;
  #pragma unroll
  for (int fm=0; fm<4; fm++){
    #pragma unroll
    for (int fn=0; fn<4; fn++){
      int col = bcol + wn*64 + fn*16 + r;
      float bias = b2[col];
      #pragma unroll
      for (int q=0; q<4; q++){
        long row = brow + wm*64 + fm*16 + hi*4 + q;
        C8[row*512 + col] = f2e8(acc[fm][fn][q]*inv32 + bias);
      }
    }
  }
}

// ---------------- fused LSTM: gates (4 rows per wave, same d) + cell ------
__global__ __launch_bounds__(256) void k_glstm(
    const float* __restrict__ x, const float* __restrict__ h_in,
    const float* __restrict__ c_in,
    const unsigned short* __restrict__ Wih, const unsigned short* __restrict__ Whh,
    const float* __restrict__ b_ih, const float* __restrict__ b_hh,
    float* __restrict__ h_out, float* __restrict__ c_out, int first)
{
  const int wid = threadIdx.x >> 6, lane = threadIdx.x & 63;
  const int d = (blockIdx.x >> 1)*4 + wid;
  const int n0 = (blockIdx.x & 1) << 4;
  float wi[4][16], wh[4][16], bias[4];
  #pragma unroll
  for (int g=0; g<4; g++){
    const int rg = g*1024 + d;
    const long wo = (long)rg*1024 + lane*16;
    short8 a0 = *(const short8*)(Wih + wo);
    short8 a1 = *(const short8*)(Wih + wo + 8);
    short8 h0v = *(const short8*)(Whh + wo);
    short8 h1v = *(const short8*)(Whh + wo + 8);
    #pragma unroll
    for (int i=0;i<8;i++){
      wi[g][i]   = b2f((unsigned short)a0[i]);  wi[g][i+8] = b2f((unsigned short)a1[i]);
      wh[g][i]   = b2f((unsigned short)h0v[i]); wh[g][i+8] = b2f((unsigned short)h1v[i]);
    }
    bias[g] = b_ih[rg] + b_hh[rg];
  }
  for (int n=n0; n<n0+16; n++){
    const float4* hp = (const float4*)(h_in + n*1024 + lane*16);
    float ha[16];
    *(float4*)(ha+0)=hp[0]; *(float4*)(ha+4)=hp[1]; *(float4*)(ha+8)=hp[2]; *(float4*)(ha+12)=hp[3];
    float s0=0.f, s1=0.f, s2=0.f, s3=0.f;
    if (first){
      #pragma unroll
      for (int i=0;i<16;i++){
        s0 += ha[i]*wh[0][i]; s1 += ha[i]*wh[1][i];
        s2 += ha[i]*wh[2][i]; s3 += ha[i]*wh[3][i];
      }
    } else {
      const float4* xp = (const float4*)(x + n*1024 + lane*16);
      float xa[16];
      *(float4*)(xa+0)=xp[0]; *(float4*)(xa+4)=xp[1]; *(float4*)(xa+8)=xp[2]; *(float4*)(xa+12)=xp[3];
      #pragma unroll
      for (int i=0;i<16;i++){
        s0 += xa[i]*wi[0][i] + ha[i]*wh[0][i];
        s1 += xa[i]*wi[1][i] + ha[i]*wh[1][i];
        s2 += xa[i]*wi[2][i] + ha[i]*wh[2][i];
        s3 += xa[i]*wi[3][i] + ha[i]*wh[3][i];
      }
    }
    #pragma unroll
    for (int o=32;o>0;o>>=1){
      s0 += __shfl_xor(s0, o); s1 += __shfl_xor(s1, o);
      s2 += __shfl_xor(s2, o); s3 += __shfl_xor(s3, o);
    }
    if (lane == 0){
      const int idx = n*1024 + d;
      float gi = sigm(s0 + bias[0]);
      float gf = sigm(s1 + bias[1]);
      float gg = tanh_f(s2 + bias[2]);
      float go = sigm(s3 + bias[3]);
      float cn = gf*c_in[idx] + gi*gg;
      c_out[idx] = cn;
      h_out[idx] = go * tanh_f(cn);
    }
  }
}

// ---------------- q projection: wave-per-2j, n split over 2 blocks --------
__global__ __launch_bounds__(256) void k_q(
    const float* __restrict__ h, const unsigned short* __restrict__ W1,
    const float* __restrict__ b1, float* __restrict__ q)
{
  const int wid = threadIdx.x >> 6, lane = threadIdx.x & 63;
  const int jgrp = blockIdx.x >> 1;
  const int n0 = (blockIdx.x & 1) << 4;
  const int j0 = (jgrp*4 + wid)*2;
  float wf[2][16], bias[2];
  #pragma unroll
  for (int jj=0;jj<2;jj++){
    const long wo = (long)(j0+jj)*1024 + lane*16;
    short8 w0 = *(const short8*)(W1 + wo);
    short8 w1 = *(const short8*)(W1 + wo + 8);
    #pragma unroll
    for (int i=0;i<8;i++){ wf[jj][i] = b2f((unsigned short)w0[i]); wf[jj][i+8] = b2f((unsigned short)w1[i]); }
    bias[jj] = b1[j0+jj];
  }
  for (int n=n0; n<n0+16; n++){
    const float4* hp = (const float4*)(h + n*1024 + lane*16);
    float ha[16];
    *(float4*)(ha+0)=hp[0]; *(float4*)(ha+4)=hp[1]; *(float4*)(ha+8)=hp[2]; *(float4*)(ha+12)=hp[3];
    float s0=0.f, s1=0.f;
    #pragma unroll
    for (int i=0;i<16;i++){ s0 += ha[i]*wf[0][i]; s1 += ha[i]*wf[1][i]; }
    #pragma unroll
    for (int o=32;o>0;o>>=1){ s0 += __shfl_xor(s0, o); s1 += __shfl_xor(s1, o); }
    if (lane == 0){ q[n*AA + j0] = s0 + bias[0]; q[n*AA + j0 + 1] = s1 + bias[1]; }
  }
}

// ---- fused attn + softmax(no-max) + x_next partials + last-block reduce --
__global__ __launch_bounds__(256) void k_attnx(
    const unsigned char* __restrict__ ep8, const float* __restrict__ qv,
    const float* __restrict__ w3, const float* __restrict__ b3p,
    const int* __restrict__ mask, const unsigned char* __restrict__ enc8,
    float* __restrict__ out, float* __restrict__ part,
    float* __restrict__ psum, float* __restrict__ x,
    int* __restrict__ cnt, int t)
{
  const int n = blockIdx.y, ch = blockIdx.x;
  const int tid = threadIdx.x;
  const int wid = tid >> 6, lane = tid & 63;
  __shared__ float p_s[64];
  __shared__ int s_old;

  float qf[8], w3f[8];
  const float4* qp = (const float4*)(qv + n*AA + lane*8);
  *(float4*)(qf+0) = qp[0]; *(float4*)(qf+4) = qp[1];
  const float4* wp = (const float4*)(w3 + lane*8);
  *(float4*)(w3f+0) = wp[0]; *(float4*)(w3f+4) = wp[1];
  const float b3v = b3p[0];

  #pragma unroll 1
  for (int li = 0; li < 16; li++){
    const int l = ch*64 + wid*16 + li;
    uint2 e = *(const uint2*)(ep8 + ((long)n*LL + l)*AA + lane*8);
    float ef[8];
    ef[0]=DEC8(e.x,0); ef[1]=DEC8(e.x,1); ef[2]=DEC8(e.x,2); ef[3]=DEC8(e.x,3);
    ef[4]=DEC8(e.y,0); ef[5]=DEC8(e.y,1); ef[6]=DEC8(e.y,2); ef[7]=DEC8(e.y,3);
    float s = 0.f;
    #pragma unroll
    for (int i=0;i<8;i++) s += tanh_f(ef[i] + qf[i]) * w3f[i];
    #pragma unroll
    for (int o=32;o>0;o>>=1) s += __shfl_xor(s, o);
    if (lane == 0){
      float a = s + b3v;
      int mk = mask[n*LL + l];
      float aout = a;
      if (!mk) aout += -1e30f;
      out[((long)n*TT + t)*LL + l] = aout;
      p_s[wid*16 + li] = mk ? EXP2(a*LOG2E) : 0.f;
    }
  }
  __syncthreads();

  const unsigned char* base = enc8 + ((long)n*LL + ch*64)*1024 + tid*4;
  float a0=0.f, a1=0.f, a2=0.f, a3=0.f;
  #pragma unroll 4
  for (int li=0; li<64; li++){
    float pv = p_s[li];
    unsigned u = *(const unsigned*)(base + (long)li*1024);
    a0 = fmaf(pv, DEC8(u,0), a0);
    a1 = fmaf(pv, DEC8(u,1), a1);
    a2 = fmaf(pv, DEC8(u,2), a2);
    a3 = fmaf(pv, DEC8(u,3), a3);
  }
  float4 o = {a0,a1,a2,a3};
  *(float4*)(part + ((long)(n*32+ch))*1024 + tid*4) = o;
  if (tid == 0){
    float S = 0.f;
    #pragma unroll
    for (int i=0;i<64;i++) S += p_s[i];
    psum[n*32 + ch] = S;
  }

  // publish, then last block per n reduces (classic threadfence reduction)
  __threadfence();
  __syncthreads();
  if (tid == 0) s_old = atomicAdd(&cnt[n], 1);
  __syncthreads();
  if (s_old == 31){
    if (tid == 0) atomicExch(&cnt[n], 0);   // self-clean for next launch
    __threadfence();
    float S = 0.f;
    #pragma unroll
    for (int c2=0; c2<32; c2++) S += psum[n*32 + c2];
    float inv = RCP(S);
    float sx=0.f, sy=0.f, sz=0.f, sw=0.f;
    #pragma unroll 1
    for (int c2=0; c2<32; c2++){
      float4 v = *(const float4*)(part + ((long)(n*32+c2))*1024 + tid*4);
      sx += v.x; sy += v.y; sz += v.z; sw += v.w;
    }
    float4 oX = {sx*inv, sy*inv, sz*inv, sw*inv};
    *(float4*)(x + n*1024 + tid*4) = oX;
  }
}

extern "C" void kernel_launch(void* const* d_in, const int* in_sizes, int n_in,
                              void* d_out, int out_size, void* d_ws, size_t ws_size,
                              hipStream_t stream){
  const float* enc_f = (const float*)d_in[0];
  const float* h0    = (const float*)d_in[1];
  const float* c0    = (const float*)d_in[2];
  const int*   mask  = (const int*)d_in[3];
  const float* Wih_f = (const float*)d_in[4];
  const float* Whh_f = (const float*)d_in[5];
  const float* b_ih  = (const float*)d_in[6];
  const float* b_hh  = (const float*)d_in[7];
  const float* W1_f  = (const float*)d_in[8];
  const float* b1    = (const float*)d_in[9];
  const float* W2_f  = (const float*)d_in[10];
  const float* b2    = (const float*)d_in[11];
  const float* w3    = (const float*)d_in[12];
  const float* b3    = (const float*)d_in[13];
  float* out = (float*)d_out;

  char* ws = (char*)d_ws;
  size_t off = 0;
  auto alloc = [&](size_t bytes){ void* p = ws + off; off += (bytes + 255) & ~255ull; return p; };
  unsigned char*  enc_8 = (unsigned char*)alloc((size_t)NB*LL*DD);     // 64 MB fp8
  unsigned char*  ep_8  = (unsigned char*)alloc((size_t)NB*LL*AA);     // 32 MB fp8
  unsigned short* Wih_b = (unsigned short*)alloc((size_t)4*DD*DD*2);
  unsigned short* Whh_b = (unsigned short*)alloc((size_t)4*DD*DD*2);
  unsigned short* W1_b  = (unsigned short*)alloc((size_t)AA*DD*2);
  unsigned char*  W2_8  = (unsigned char*)alloc((size_t)AA*DD);        // fp8 x32
  float* hA    = (float*)alloc((size_t)NB*DD*4);
  float* hB    = (float*)alloc((size_t)NB*DD*4);
  float* cbuf  = (float*)alloc((size_t)NB*DD*4);
  float* xbuf  = (float*)alloc((size_t)NB*DD*4);
  float* qbuf  = (float*)alloc((size_t)NB*AA*4);
  float* part  = (float*)alloc((size_t)NB*32*DD*4);
  float* psum  = (float*)alloc((size_t)NB*32*4);
  int*   cnt   = (int*)alloc((size_t)NB*4);

  hipMemsetAsync(cnt, 0, (size_t)NB*4, stream);
  k_cvt_enc<<<4096,256,0,stream>>>(enc_f, enc_8, (long)NB*LL*DD/8);
  k_cvt4<<<4608,256,0,stream>>>(Wih_f, Whh_f, W1_f, W2_f,
                                Wih_b, Whh_b, W1_b, W2_8,
                                (long)4*DD*DD/8, (long)4*DD*DD/8,
                                (long)AA*DD/8, (long)AA*DD/8);
  k_gemm8<<<dim3(512,4),256,0,stream>>>(enc_8, W2_8, b2, ep_8);

  float* hcur = hA; float* hnxt = hB;
  for (int t=0; t<TT; t++){
    k_glstm<<<512,256,0,stream>>>(xbuf,
                                  t==0 ? h0 : hcur,
                                  t==0 ? c0 : cbuf,
                                  Wih_b, Whh_b, b_ih, b_hh,
                                  hnxt, cbuf, t==0 ? 1 : 0);
    k_q<<<128,256,0,stream>>>(hnxt, W1_b, b1, qbuf);
    k_attnx<<<dim3(32,NB),256,0,stream>>>(ep_8, qbuf, w3, b3, mask, enc_8,
                                          out, part, psum, xbuf, cnt, t);
    float* tmp = hcur; hcur = hnxt; hnxt = tmp;
  }
}

// Round 16
// 765.887 us; speedup vs baseline: 2.1087x; 2.1087x over previous
//
#include <hip/hip_runtime.h>

#define NB 32
#define LL 2048
#define DD 1024      // D2
#define AA 512       // ATTN
#define TT 8
#define LOG2E 1.4426950408889634f

typedef short short8 __attribute__((ext_vector_type(8)));
typedef float f32x4 __attribute__((ext_vector_type(4)));

#if __has_builtin(__builtin_amdgcn_exp2f)
#define EXP2(x) __builtin_amdgcn_exp2f(x)
#else
#define EXP2(x) exp2f(x)
#endif
#if __has_builtin(__builtin_amdgcn_rcpf)
#define RCP(x) __builtin_amdgcn_rcpf(x)
#else
#define RCP(x) (1.0f/(x))
#endif

__device__ __forceinline__ unsigned short f2b(float f){
  union { float f; unsigned u; } v; v.f = f;
  unsigned r = v.u + 0x7fffu + ((v.u >> 16) & 1u);
  return (unsigned short)(r >> 16);
}
__device__ __forceinline__ float b2f(unsigned short b){
  union { unsigned u; float f; } v; v.u = ((unsigned)b) << 16;
  return v.f;
}
__device__ __forceinline__ float sigm(float x){
  return RCP(1.f + EXP2(-x * LOG2E));
}
__device__ __forceinline__ float tanh_f(float x){
  return 2.f * RCP(1.f + EXP2(-2.f * LOG2E * x)) - 1.f;
}
__device__ __forceinline__ void gll16(const void* g, void* l){
  __builtin_amdgcn_global_load_lds(
      (const __attribute__((address_space(1))) unsigned int*)(g),
      (__attribute__((address_space(3))) unsigned int*)(l),
      16, 0, 0);
}

// ---- fp8 e4m3 (OCP) encode/decode, HW builtin with SW fallback ----
__device__ __forceinline__ unsigned char sw_enc_e4m3(float f){
  union{float f;unsigned u;} v; v.f = f;
  unsigned s = (v.u>>31)<<7;
  float a = fabsf(f);
  if (a < 0.015625f){
    int q = (int)(a*512.f + 0.5f);
    if (q > 7) return s | (1<<3);
    return s | q;
  }
  int e = ((v.u>>23)&255) - 127;
  unsigned m = ((v.u & 0x7FFFFF) + 0x80000) >> 20;
  if (m == 8){ m = 0; e++; }
  int eb = e + 7;
  if (eb > 15){ eb = 15; m = 6; }
  if (eb <= 0){
    int q = (int)(a*512.f + 0.5f); if (q>7) q=7;
    return s | q;
  }
  return s | (eb<<3) | m;
}
__device__ __forceinline__ unsigned char f2e8(float f){
#if __has_builtin(__builtin_amdgcn_cvt_pk_fp8_f32)
  return (unsigned char)(__builtin_amdgcn_cvt_pk_fp8_f32(f, f, 0, false) & 0xFF);
#else
  return sw_enc_e4m3(f);
#endif
}
__device__ __forceinline__ float sw_dec_e4m3(unsigned char c){
  unsigned s = c>>7, e = (c>>3)&15, m = c&7;
  if (e){ union{unsigned u;float f;} x; x.u = (s<<31)|((e+120)<<23)|(m<<20); return x.f; }
  float r = (float)m * 0.001953125f;
  return s ? -r : r;
}
#if __has_builtin(__builtin_amdgcn_cvt_f32_fp8)
#define DEC8(word, sel) __builtin_amdgcn_cvt_f32_fp8((int)(word), (sel))
#else
#define DEC8(word, sel) sw_dec_e4m3((unsigned char)(((word) >> ((sel)*8)) & 0xFF))
#endif

// ---------------- enc cvt: fp32 -> fp8 only ----------------
__global__ __launch_bounds__(256) void k_cvt_enc(const float* __restrict__ in,
                                                 unsigned char* __restrict__ o8,
                                                 long n8){
  long stride = (long)gridDim.x * 256;
  for (long i = (long)blockIdx.x*256 + threadIdx.x; i < n8; i += stride){
    const float4* ip = (const float4*)(in + i*8);
    float4 a = ip[0], b = ip[1];
    uint2 p;
    p.x = (unsigned)f2e8(a.x) | ((unsigned)f2e8(a.y)<<8) |
          ((unsigned)f2e8(a.z)<<16) | ((unsigned)f2e8(a.w)<<24);
    p.y = (unsigned)f2e8(b.x) | ((unsigned)f2e8(b.y)<<8) |
          ((unsigned)f2e8(b.z)<<16) | ((unsigned)f2e8(b.w)<<24);
    *(uint2*)(o8 + i*8) = p;
  }
}

// ---------------- weight cvts: Wih/Whh/W1 -> bf16, W2 -> fp8 x32 ----------
__global__ __launch_bounds__(256) void k_cvt4(
    const float* __restrict__ s0, const float* __restrict__ s1,
    const float* __restrict__ s2, const float* __restrict__ s3,
    unsigned short* __restrict__ d0, unsigned short* __restrict__ d1,
    unsigned short* __restrict__ d2, unsigned char* __restrict__ d3,
    long c0, long c1, long c2, long c3)
{
  long i = (long)blockIdx.x*256 + threadIdx.x;
  long idx = i;
  const float* s; unsigned short* d;
  if (idx < c0){ s = s0; d = d0; }
  else { idx -= c0;
    if (idx < c1){ s = s1; d = d1; }
    else { idx -= c1;
      if (idx < c2){ s = s2; d = d2; }
      else {
        idx -= c2; if (idx >= c3) return;
        const float4* ip = (const float4*)(s3 + idx*8);
        float4 a = ip[0], b = ip[1];
        uint2 p;
        p.x = (unsigned)f2e8(a.x*32.f) | ((unsigned)f2e8(a.y*32.f)<<8) |
              ((unsigned)f2e8(a.z*32.f)<<16) | ((unsigned)f2e8(a.w*32.f)<<24);
        p.y = (unsigned)f2e8(b.x*32.f) | ((unsigned)f2e8(b.y*32.f)<<8) |
              ((unsigned)f2e8(b.z*32.f)<<16) | ((unsigned)f2e8(b.w*32.f)<<24);
        *(uint2*)(d3 + idx*8) = p;
        return;
      } } }
  const float4* ip = (const float4*)(s + idx*8);
  float4 a = ip[0], b = ip[1];
  uint4 o;
  o.x = (unsigned)f2b(a.x) | ((unsigned)f2b(a.y) << 16);
  o.y = (unsigned)f2b(a.z) | ((unsigned)f2b(a.w) << 16);
  o.z = (unsigned)f2b(b.x) | ((unsigned)f2b(b.y) << 16);
  o.w = (unsigned)f2b(b.z) | ((unsigned)f2b(b.w) << 16);
  *(uint4*)(d + idx*8) = o;
}

// ---------------- enc_proj GEMM, fp8 x fp8, 128x256 tile ------------------
// BK=64, linear LDS (As 8KB, Bs 16KB), m97-style gll16 staging.
// A/B fragment loaders byte-identical from row-major [.,K] -> kappa cancels.
__global__ __launch_bounds__(256) void k_gemm8(
    const unsigned char* __restrict__ A,   // [65536,1024] fp8 enc
    const unsigned char* __restrict__ Bt,  // [512,1024] fp8 (W2*32)
    const float* __restrict__ b2,
    unsigned char* __restrict__ C8)        // [65536,512] fp8 ep
{
  __shared__ unsigned char As[128*64];
  __shared__ unsigned char Bs[256*64];
  const int tid = threadIdx.x;
  const int wid = tid >> 6, lane = tid & 63;
  const int wm = wid >> 1, wn = wid & 1;
  const int hi = lane >> 4, r = lane & 15;
  const long brow = (long)blockIdx.x * 128;
  const int bcol = blockIdx.y * 256;
  // staging geometry: wave w, call j writes LDS rows [w*16 + j*64, +16)
  const int srow = wid*16 + (lane >> 2);
  const int scol = (lane & 3) * 16;
  const unsigned char* aS0 = A + (brow + srow)*1024 + scol;        // j=0
  const unsigned char* aS1 = A + (brow + srow + 64)*1024 + scol;   // j=1
  const unsigned char* bS0 = Bt + (long)(bcol + srow)*1024 + scol;
  const unsigned char* bS1 = Bt + (long)(bcol + srow + 64)*1024 + scol;
  const unsigned char* bS2 = Bt + (long)(bcol + srow + 128)*1024 + scol;
  const unsigned char* bS3 = Bt + (long)(bcol + srow + 192)*1024 + scol;
  char* aD = (char*)As + wid*1024;
  char* bD = (char*)Bs + wid*1024;

  f32x4 acc[4][8];
  #pragma unroll
  for (int i=0;i<4;i++)
    #pragma unroll
    for (int j=0;j<8;j++) acc[i][j] = (f32x4){0.f,0.f,0.f,0.f};

  for (int k0 = 0; k0 < 1024; k0 += 64){
    __syncthreads();
    gll16(aS0 + k0, aD);
    gll16(aS1 + k0, aD + 4096);
    gll16(bS0 + k0, bD);
    gll16(bS1 + k0, bD + 4096);
    gll16(bS2 + k0, bD + 8192);
    gll16(bS3 + k0, bD + 12288);
    __syncthreads();
    long af[4][2], bfr[8][2];
    #pragma unroll
    for (int fm=0; fm<4; fm++){
      af[fm][0] = *(const long*)((const char*)As + (wm*64 + fm*16 + r)*64 + hi*8);
      af[fm][1] = *(const long*)((const char*)As + (wm*64 + fm*16 + r)*64 + 32 + hi*8);
    }
    #pragma unroll
    for (int fn=0; fn<8; fn++){
      bfr[fn][0] = *(const long*)((const char*)Bs + (wn*128 + fn*16 + r)*64 + hi*8);
      bfr[fn][1] = *(const long*)((const char*)Bs + (wn*128 + fn*16 + r)*64 + 32 + hi*8);
    }
    #pragma unroll
    for (int fm=0; fm<4; fm++)
      #pragma unroll
      for (int fn=0; fn<8; fn++){
        acc[fm][fn] = __builtin_amdgcn_mfma_f32_16x16x32_fp8_fp8(af[fm][0], bfr[fn][0], acc[fm][fn], 0, 0, 0);
        acc[fm][fn] = __builtin_amdgcn_mfma_f32_16x16x32_fp8_fp8(af[fm][1], bfr[fn][1], acc[fm][fn], 0, 0, 0);
      }
  }
  // C/D layout (shape-determined): col = lane&15, row = (lane>>4)*4 + q
  const float inv32 = 1.f/32.f;
  #pragma unroll
  for (int fm=0; fm<4; fm++){
    #pragma unroll
    for (int fn=0; fn<8; fn++){
      int col = bcol + wn*128 + fn*16 + r;
      float bias = b2[col];
      #pragma unroll
      for (int q=0; q<4; q++){
        long row = brow + wm*64 + fm*16 + hi*4 + q;
        C8[row*512 + col] = f2e8(acc[fm][fn][q]*inv32 + bias);
      }
    }
  }
}

// ---------------- fused LSTM: gates (4 rows per wave, same d) + cell ------
__global__ __launch_bounds__(256) void k_glstm(
    const float* __restrict__ x, const float* __restrict__ h_in,
    const float* __restrict__ c_in,
    const unsigned short* __restrict__ Wih, const unsigned short* __restrict__ Whh,
    const float* __restrict__ b_ih, const float* __restrict__ b_hh,
    float* __restrict__ h_out, float* __restrict__ c_out, int first)
{
  const int wid = threadIdx.x >> 6, lane = threadIdx.x & 63;
  const int d = (blockIdx.x >> 1)*4 + wid;
  const int n0 = (blockIdx.x & 1) << 4;
  float wi[4][16], wh[4][16], bias[4];
  #pragma unroll
  for (int g=0; g<4; g++){
    const int rg = g*1024 + d;
    const long wo = (long)rg*1024 + lane*16;
    short8 a0 = *(const short8*)(Wih + wo);
    short8 a1 = *(const short8*)(Wih + wo + 8);
    short8 h0v = *(const short8*)(Whh + wo);
    short8 h1v = *(const short8*)(Whh + wo + 8);
    #pragma unroll
    for (int i=0;i<8;i++){
      wi[g][i]   = b2f((unsigned short)a0[i]);  wi[g][i+8] = b2f((unsigned short)a1[i]);
      wh[g][i]   = b2f((unsigned short)h0v[i]); wh[g][i+8] = b2f((unsigned short)h1v[i]);
    }
    bias[g] = b_ih[rg] + b_hh[rg];
  }
  for (int n=n0; n<n0+16; n++){
    const float4* hp = (const float4*)(h_in + n*1024 + lane*16);
    float ha[16];
    *(float4*)(ha+0)=hp[0]; *(float4*)(ha+4)=hp[1]; *(float4*)(ha+8)=hp[2]; *(float4*)(ha+12)=hp[3];
    float s0=0.f, s1=0.f, s2=0.f, s3=0.f;
    if (first){
      #pragma unroll
      for (int i=0;i<16;i++){
        s0 += ha[i]*wh[0][i]; s1 += ha[i]*wh[1][i];
        s2 += ha[i]*wh[2][i]; s3 += ha[i]*wh[3][i];
      }
    } else {
      const float4* xp = (const float4*)(x + n*1024 + lane*16);
      float xa[16];
      *(float4*)(xa+0)=xp[0]; *(float4*)(xa+4)=xp[1]; *(float4*)(xa+8)=xp[2]; *(float4*)(xa+12)=xp[3];
      #pragma unroll
      for (int i=0;i<16;i++){
        s0 += xa[i]*wi[0][i] + ha[i]*wh[0][i];
        s1 += xa[i]*wi[1][i] + ha[i]*wh[1][i];
        s2 += xa[i]*wi[2][i] + ha[i]*wh[2][i];
        s3 += xa[i]*wi[3][i] + ha[i]*wh[3][i];
      }
    }
    #pragma unroll
    for (int o=32;o>0;o>>=1){
      s0 += __shfl_xor(s0, o); s1 += __shfl_xor(s1, o);
      s2 += __shfl_xor(s2, o); s3 += __shfl_xor(s3, o);
    }
    if (lane == 0){
      const int idx = n*1024 + d;
      float gi = sigm(s0 + bias[0]);
      float gf = sigm(s1 + bias[1]);
      float gg = tanh_f(s2 + bias[2]);
      float go = sigm(s3 + bias[3]);
      float cn = gf*c_in[idx] + gi*gg;
      c_out[idx] = cn;
      h_out[idx] = go * tanh_f(cn);
    }
  }
}

// ---------------- q projection: wave-per-2j, n split over 2 blocks --------
__global__ __launch_bounds__(256) void k_q(
    const float* __restrict__ h, const unsigned short* __restrict__ W1,
    const float* __restrict__ b1, float* __restrict__ q)
{
  const int wid = threadIdx.x >> 6, lane = threadIdx.x & 63;
  const int jgrp = blockIdx.x >> 1;
  const int n0 = (blockIdx.x & 1) << 4;
  const int j0 = (jgrp*4 + wid)*2;
  float wf[2][16], bias[2];
  #pragma unroll
  for (int jj=0;jj<2;jj++){
    const long wo = (long)(j0+jj)*1024 + lane*16;
    short8 w0 = *(const short8*)(W1 + wo);
    short8 w1 = *(const short8*)(W1 + wo + 8);
    #pragma unroll
    for (int i=0;i<8;i++){ wf[jj][i] = b2f((unsigned short)w0[i]); wf[jj][i+8] = b2f((unsigned short)w1[i]); }
    bias[jj] = b1[j0+jj];
  }
  for (int n=n0; n<n0+16; n++){
    const float4* hp = (const float4*)(h + n*1024 + lane*16);
    float ha[16];
    *(float4*)(ha+0)=hp[0]; *(float4*)(ha+4)=hp[1]; *(float4*)(ha+8)=hp[2]; *(float4*)(ha+12)=hp[3];
    float s0=0.f, s1=0.f;
    #pragma unroll
    for (int i=0;i<16;i++){ s0 += ha[i]*wf[0][i]; s1 += ha[i]*wf[1][i]; }
    #pragma unroll
    for (int o=32;o>0;o>>=1){ s0 += __shfl_xor(s0, o); s1 += __shfl_xor(s1, o); }
    if (lane == 0){ q[n*AA + j0] = s0 + bias[0]; q[n*AA + j0 + 1] = s1 + bias[1]; }
  }
}

// ---------------- fused attn + softmax(no-max) + x_next partials (fp8) ----
__global__ __launch_bounds__(256) void k_attnx(
    const unsigned char* __restrict__ ep8, const float* __restrict__ qv,
    const float* __restrict__ w3, const float* __restrict__ b3p,
    const int* __restrict__ mask, const unsigned char* __restrict__ enc8,
    float* __restrict__ out, float* __restrict__ part,
    float* __restrict__ psum, int t)
{
  const int n = blockIdx.y, ch = blockIdx.x;
  const int tid = threadIdx.x;
  const int wid = tid >> 6, lane = tid & 63;
  __shared__ float p_s[64];

  float qf[8], w3f[8];
  const float4* qp = (const float4*)(qv + n*AA + lane*8);
  *(float4*)(qf+0) = qp[0]; *(float4*)(qf+4) = qp[1];
  const float4* wp = (const float4*)(w3 + lane*8);
  *(float4*)(w3f+0) = wp[0]; *(float4*)(w3f+4) = wp[1];
  const float b3v = b3p[0];

  #pragma unroll 1
  for (int li = 0; li < 16; li++){
    const int l = ch*64 + wid*16 + li;
    uint2 e = *(const uint2*)(ep8 + ((long)n*LL + l)*AA + lane*8);
    float ef[8];
    ef[0]=DEC8(e.x,0); ef[1]=DEC8(e.x,1); ef[2]=DEC8(e.x,2); ef[3]=DEC8(e.x,3);
    ef[4]=DEC8(e.y,0); ef[5]=DEC8(e.y,1); ef[6]=DEC8(e.y,2); ef[7]=DEC8(e.y,3);
    float s = 0.f;
    #pragma unroll
    for (int i=0;i<8;i++) s += tanh_f(ef[i] + qf[i]) * w3f[i];
    #pragma unroll
    for (int o=32;o>0;o>>=1) s += __shfl_xor(s, o);
    if (lane == 0){
      float a = s + b3v;
      int mk = mask[n*LL + l];
      float aout = a;
      if (!mk) aout += -1e30f;
      out[((long)n*TT + t)*LL + l] = aout;
      p_s[wid*16 + li] = mk ? EXP2(a*LOG2E) : 0.f;
    }
  }
  __syncthreads();

  const unsigned char* base = enc8 + ((long)n*LL + ch*64)*1024 + tid*4;
  float a0=0.f, a1=0.f, a2=0.f, a3=0.f;
  #pragma unroll 4
  for (int li=0; li<64; li++){
    float pv = p_s[li];
    unsigned u = *(const unsigned*)(base + (long)li*1024);
    a0 = fmaf(pv, DEC8(u,0), a0);
    a1 = fmaf(pv, DEC8(u,1), a1);
    a2 = fmaf(pv, DEC8(u,2), a2);
    a3 = fmaf(pv, DEC8(u,3), a3);
  }
  float4 o = {a0,a1,a2,a3};
  *(float4*)(part + ((long)(n*32+ch))*1024 + tid*4) = o;
  if (tid == 0){
    float S = 0.f;
    #pragma unroll
    for (int i=0;i<64;i++) S += p_s[i];
    psum[n*32 + ch] = S;
  }
}

// ---------------- reduce partials -> x (divide by total sum) --------------
__global__ __launch_bounds__(256) void k_xreduce(const float* __restrict__ part,
                                                 const float* __restrict__ psum,
                                                 float* __restrict__ x){
  int idx = blockIdx.x*256 + threadIdx.x;
  int n = idx >> 10, d = idx & 1023;
  float S = 0.f;
  #pragma unroll
  for (int ch=0; ch<32; ch++) S += psum[n*32 + ch];
  float s = 0.f;
  #pragma unroll
  for (int ch=0; ch<32; ch++) s += part[((long)(n*32+ch))*1024 + d];
  x[idx] = s * RCP(S);
}

extern "C" void kernel_launch(void* const* d_in, const int* in_sizes, int n_in,
                              void* d_out, int out_size, void* d_ws, size_t ws_size,
                              hipStream_t stream){
  const float* enc_f = (const float*)d_in[0];
  const float* h0    = (const float*)d_in[1];
  const float* c0    = (const float*)d_in[2];
  const int*   mask  = (const int*)d_in[3];
  const float* Wih_f = (const float*)d_in[4];
  const float* Whh_f = (const float*)d_in[5];
  const float* b_ih  = (const float*)d_in[6];
  const float* b_hh  = (const float*)d_in[7];
  const float* W1_f  = (const float*)d_in[8];
  const float* b1    = (const float*)d_in[9];
  const float* W2_f  = (const float*)d_in[10];
  const float* b2    = (const float*)d_in[11];
  const float* w3    = (const float*)d_in[12];
  const float* b3    = (const float*)d_in[13];
  float* out = (float*)d_out;

  char* ws = (char*)d_ws;
  size_t off = 0;
  auto alloc = [&](size_t bytes){ void* p = ws + off; off += (bytes + 255) & ~255ull; return p; };
  unsigned char*  enc_8 = (unsigned char*)alloc((size_t)NB*LL*DD);     // 64 MB fp8
  unsigned char*  ep_8  = (unsigned char*)alloc((size_t)NB*LL*AA);     // 32 MB fp8
  unsigned short* Wih_b = (unsigned short*)alloc((size_t)4*DD*DD*2);
  unsigned short* Whh_b = (unsigned short*)alloc((size_t)4*DD*DD*2);
  unsigned short* W1_b  = (unsigned short*)alloc((size_t)AA*DD*2);
  unsigned char*  W2_8  = (unsigned char*)alloc((size_t)AA*DD);        // fp8 x32
  float* hA    = (float*)alloc((size_t)NB*DD*4);
  float* hB    = (float*)alloc((size_t)NB*DD*4);
  float* cbuf  = (float*)alloc((size_t)NB*DD*4);
  float* xbuf  = (float*)alloc((size_t)NB*DD*4);
  float* qbuf  = (float*)alloc((size_t)NB*AA*4);
  float* part  = (float*)alloc((size_t)NB*32*DD*4);
  float* psum  = (float*)alloc((size_t)NB*32*4);

  k_cvt_enc<<<4096,256,0,stream>>>(enc_f, enc_8, (long)NB*LL*DD/8);
  k_cvt4<<<4608,256,0,stream>>>(Wih_f, Whh_f, W1_f, W2_f,
                                Wih_b, Whh_b, W1_b, W2_8,
                                (long)4*DD*DD/8, (long)4*DD*DD/8,
                                (long)AA*DD/8, (long)AA*DD/8);
  k_gemm8<<<dim3(512,2),256,0,stream>>>(enc_8, W2_8, b2, ep_8);

  float* hcur = hA; float* hnxt = hB;
  for (int t=0; t<TT; t++){
    k_glstm<<<512,256,0,stream>>>(xbuf,
                                  t==0 ? h0 : hcur,
                                  t==0 ? c0 : cbuf,
                                  Wih_b, Whh_b, b_ih, b_hh,
                                  hnxt, cbuf, t==0 ? 1 : 0);
    k_q<<<128,256,0,stream>>>(hnxt, W1_b, b1, qbuf);
    k_attnx<<<dim3(32,NB),256,0,stream>>>(ep_8, qbuf, w3, b3, mask, enc_8,
                                          out, part, psum, t);
    k_xreduce<<<128,256,0,stream>>>(part, psum, xbuf);
    float* tmp = hcur; hcur = hnxt; hnxt = tmp;
  }
}

// Round 18
// 669.035 us; speedup vs baseline: 2.4140x; 1.1448x over previous
//
#include <hip/hip_runtime.h>

#define NB 32
#define LL 2048
#define DD 1024      // D2
#define AA 512       // ATTN
#define TT 8
#define LOG2E 1.4426950408889634f

typedef short short8 __attribute__((ext_vector_type(8)));
typedef float f32x4 __attribute__((ext_vector_type(4)));

#if __has_builtin(__builtin_amdgcn_exp2f)
#define EXP2(x) __builtin_amdgcn_exp2f(x)
#else
#define EXP2(x) exp2f(x)
#endif
#if __has_builtin(__builtin_amdgcn_rcpf)
#define RCP(x) __builtin_amdgcn_rcpf(x)
#else
#define RCP(x) (1.0f/(x))
#endif

__device__ __forceinline__ unsigned short f2b(float f){
  union { float f; unsigned u; } v; v.f = f;
  unsigned r = v.u + 0x7fffu + ((v.u >> 16) & 1u);
  return (unsigned short)(r >> 16);
}
__device__ __forceinline__ float b2f(unsigned short b){
  union { unsigned u; float f; } v; v.u = ((unsigned)b) << 16;
  return v.f;
}
__device__ __forceinline__ float sigm(float x){
  return RCP(1.f + EXP2(-x * LOG2E));
}
__device__ __forceinline__ float tanh_f(float x){
  return 2.f * RCP(1.f + EXP2(-2.f * LOG2E * x)) - 1.f;
}
__device__ __forceinline__ void gll16(const void* g, void* l){
  __builtin_amdgcn_global_load_lds(
      (const __attribute__((address_space(1))) unsigned int*)(g),
      (__attribute__((address_space(3))) unsigned int*)(l),
      16, 0, 0);
}

// ---- fp8 e4m3 (OCP) encode/decode, HW builtin with SW fallback ----
__device__ __forceinline__ unsigned char sw_enc_e4m3(float f){
  union{float f;unsigned u;} v; v.f = f;
  unsigned s = (v.u>>31)<<7;
  float a = fabsf(f);
  if (a < 0.015625f){
    int q = (int)(a*512.f + 0.5f);
    if (q > 7) return s | (1<<3);
    return s | q;
  }
  int e = ((v.u>>23)&255) - 127;
  unsigned m = ((v.u & 0x7FFFFF) + 0x80000) >> 20;
  if (m == 8){ m = 0; e++; }
  int eb = e + 7;
  if (eb > 15){ eb = 15; m = 6; }
  if (eb <= 0){
    int q = (int)(a*512.f + 0.5f); if (q>7) q=7;
    return s | q;
  }
  return s | (eb<<3) | m;
}
__device__ __forceinline__ unsigned char f2e8(float f){
#if __has_builtin(__builtin_amdgcn_cvt_pk_fp8_f32)
  return (unsigned char)(__builtin_amdgcn_cvt_pk_fp8_f32(f, f, 0, false) & 0xFF);
#else
  return sw_enc_e4m3(f);
#endif
}
__device__ __forceinline__ float sw_dec_e4m3(unsigned char c){
  unsigned s = c>>7, e = (c>>3)&15, m = c&7;
  if (e){ union{unsigned u;float f;} x; x.u = (s<<31)|((e+120)<<23)|(m<<20); return x.f; }
  float r = (float)m * 0.001953125f;
  return s ? -r : r;
}
#if __has_builtin(__builtin_amdgcn_cvt_f32_fp8)
#define DEC8(word, sel) __builtin_amdgcn_cvt_f32_fp8((int)(word), (sel))
#else
#define DEC8(word, sel) sw_dec_e4m3((unsigned char)(((word) >> ((sel)*8)) & 0xFF))
#endif

// ---------------- enc cvt: fp32 -> fp8 only ----------------
__global__ __launch_bounds__(256) void k_cvt_enc(const float* __restrict__ in,
                                                 unsigned char* __restrict__ o8,
                                                 long n8){
  long stride = (long)gridDim.x * 256;
  for (long i = (long)blockIdx.x*256 + threadIdx.x; i < n8; i += stride){
    const float4* ip = (const float4*)(in + i*8);
    float4 a = ip[0], b = ip[1];
    uint2 p;
    p.x = (unsigned)f2e8(a.x) | ((unsigned)f2e8(a.y)<<8) |
          ((unsigned)f2e8(a.z)<<16) | ((unsigned)f2e8(a.w)<<24);
    p.y = (unsigned)f2e8(b.x) | ((unsigned)f2e8(b.y)<<8) |
          ((unsigned)f2e8(b.z)<<16) | ((unsigned)f2e8(b.w)<<24);
    *(uint2*)(o8 + i*8) = p;
  }
}

// ---------------- weight cvts: Wih/Whh/W1 -> bf16, W2 -> fp8 x32 ----------
__global__ __launch_bounds__(256) void k_cvt4(
    const float* __restrict__ s0, const float* __restrict__ s1,
    const float* __restrict__ s2, const float* __restrict__ s3,
    unsigned short* __restrict__ d0, unsigned short* __restrict__ d1,
    unsigned short* __restrict__ d2, unsigned char* __restrict__ d3,
    long c0, long c1, long c2, long c3)
{
  long i = (long)blockIdx.x*256 + threadIdx.x;
  long idx = i;
  const float* s; unsigned short* d;
  if (idx < c0){ s = s0; d = d0; }
  else { idx -= c0;
    if (idx < c1){ s = s1; d = d1; }
    else { idx -= c1;
      if (idx < c2){ s = s2; d = d2; }
      else {
        idx -= c2; if (idx >= c3) return;
        const float4* ip = (const float4*)(s3 + idx*8);
        float4 a = ip[0], b = ip[1];
        uint2 p;
        p.x = (unsigned)f2e8(a.x*32.f) | ((unsigned)f2e8(a.y*32.f)<<8) |
              ((unsigned)f2e8(a.z*32.f)<<16) | ((unsigned)f2e8(a.w*32.f)<<24);
        p.y = (unsigned)f2e8(b.x*32.f) | ((unsigned)f2e8(b.y*32.f)<<8) |
              ((unsigned)f2e8(b.z*32.f)<<16) | ((unsigned)f2e8(b.w*32.f)<<24);
        *(uint2*)(d3 + idx*8) = p;
        return;
      } } }
  const float4* ip = (const float4*)(s + idx*8);
  float4 a = ip[0], b = ip[1];
  uint4 o;
  o.x = (unsigned)f2b(a.x) | ((unsigned)f2b(a.y) << 16);
  o.y = (unsigned)f2b(a.z) | ((unsigned)f2b(a.w) << 16);
  o.z = (unsigned)f2b(b.x) | ((unsigned)f2b(b.y) << 16);
  o.w = (unsigned)f2b(b.z) | ((unsigned)f2b(b.w) << 16);
  *(uint4*)(d + idx*8) = o;
}

// ---------------- enc_proj GEMM, fp8 x fp8, 128x128 tile (r14 geometry) ----
// BK=64, linear LDS dest + 16B-granular XOR swizzle applied on BOTH the
// per-lane global source column (write side) and the fragment reads
// (rule #21). chunk' = chunk ^ ((row>>1)&3) -> b64 reads hit the 512B/instr
// floor (16 distinct 2-bank slots) instead of 8-way conflicts.
__global__ __launch_bounds__(256) void k_gemm8(
    const unsigned char* __restrict__ A,   // [65536,1024] fp8 enc
    const unsigned char* __restrict__ Bt,  // [512,1024] fp8 (W2*32)
    const float* __restrict__ b2,
    unsigned char* __restrict__ C8)        // [65536,512] fp8 ep
{
  __shared__ unsigned char As[128*64];
  __shared__ unsigned char Bs[128*64];
  const int tid = threadIdx.x;
  const int wid = tid >> 6, lane = tid & 63;
  const int wm = wid >> 1, wn = wid & 1;
  const int hi = lane >> 4, r = lane & 15;
  const long brow = (long)blockIdx.x * 128;
  const int bcol = blockIdx.y * 128;
  const int srow = wid*32 + (lane >> 2);
  // write-side swizzle: row&3-pair index is (lane>>3)&3 for staged rows
  const int scol = (((lane & 3) ^ ((lane >> 3) & 3)) << 4);
  const unsigned char* aS0 = A + (brow + srow)*1024 + scol;
  const unsigned char* aS1 = A + (brow + srow + 16)*1024 + scol;
  const unsigned char* bS0 = Bt + (long)(bcol + srow)*1024 + scol;
  const unsigned char* bS1 = Bt + (long)(bcol + srow + 16)*1024 + scol;
  char* aD = (char*)As + wid*2048;
  char* bD = (char*)Bs + wid*2048;

  f32x4 acc[4][4];
  #pragma unroll
  for (int i=0;i<4;i++)
    #pragma unroll
    for (int j=0;j<4;j++) acc[i][j] = (f32x4){0.f,0.f,0.f,0.f};

  const int sw = (r >> 1) & 3;           // read-side swizzle key
  const int c0 = hi >> 1;
  const int h8 = (hi & 1) * 8;
  const int p0 = ((c0 ^ sw) << 4) + h8;  // k-half 0 chunk offset; k-half 1 = p0^32

  for (int k0 = 0; k0 < 1024; k0 += 64){
    __syncthreads();
    gll16(aS0 + k0, aD);
    gll16(aS1 + k0, aD + 1024);
    gll16(bS0 + k0, bD);
    gll16(bS1 + k0, bD + 1024);
    __syncthreads();
    long af[4][2], bfr[4][2];
    #pragma unroll
    for (int fm=0; fm<4; fm++){
      const char* base = (const char*)As + (wm*64 + fm*16 + r)*64;
      af[fm][0] = *(const long*)(base + p0);
      af[fm][1] = *(const long*)(base + (p0 ^ 32));
    }
    #pragma unroll
    for (int fn=0; fn<4; fn++){
      const char* base = (const char*)Bs + (wn*64 + fn*16 + r)*64;
      bfr[fn][0] = *(const long*)(base + p0);
      bfr[fn][1] = *(const long*)(base + (p0 ^ 32));
    }
    #pragma unroll
    for (int fm=0; fm<4; fm++)
      #pragma unroll
      for (int fn=0; fn<4; fn++){
        acc[fm][fn] = __builtin_amdgcn_mfma_f32_16x16x32_fp8_fp8(af[fm][0], bfr[fn][0], acc[fm][fn], 0, 0, 0);
        acc[fm][fn] = __builtin_amdgcn_mfma_f32_16x16x32_fp8_fp8(af[fm][1], bfr[fn][1], acc[fm][fn], 0, 0, 0);
      }
  }
  const float inv32 = 1.f/32.f;
  #pragma unroll
  for (int fm=0; fm<4; fm++){
    #pragma unroll
    for (int fn=0; fn<4; fn++){
      int col = bcol + wn*64 + fn*16 + r;
      float bias = b2[col];
      #pragma unroll
      for (int q=0; q<4; q++){
        long row = brow + wm*64 + fm*16 + hi*4 + q;
        C8[row*512 + col] = f2e8(acc[fm][fn][q]*inv32 + bias);
      }
    }
  }
}

// ---------------- fused LSTM: gates (4 rows per wave, same d) + cell ------
__global__ __launch_bounds__(256) void k_glstm(
    const float* __restrict__ x, const float* __restrict__ h_in,
    const float* __restrict__ c_in,
    const unsigned short* __restrict__ Wih, const unsigned short* __restrict__ Whh,
    const float* __restrict__ b_ih, const float* __restrict__ b_hh,
    float* __restrict__ h_out, float* __restrict__ c_out, int first)
{
  const int wid = threadIdx.x >> 6, lane = threadIdx.x & 63;
  const int d = (blockIdx.x >> 1)*4 + wid;
  const int n0 = (blockIdx.x & 1) << 4;
  float wi[4][16], wh[4][16], bias[4];
  #pragma unroll
  for (int g=0; g<4; g++){
    const int rg = g*1024 + d;
    const long wo = (long)rg*1024 + lane*16;
    short8 a0 = *(const short8*)(Wih + wo);
    short8 a1 = *(const short8*)(Wih + wo + 8);
    short8 h0v = *(const short8*)(Whh + wo);
    short8 h1v = *(const short8*)(Whh + wo + 8);
    #pragma unroll
    for (int i=0;i<8;i++){
      wi[g][i]   = b2f((unsigned short)a0[i]);  wi[g][i+8] = b2f((unsigned short)a1[i]);
      wh[g][i]   = b2f((unsigned short)h0v[i]); wh[g][i+8] = b2f((unsigned short)h1v[i]);
    }
    bias[g] = b_ih[rg] + b_hh[rg];
  }
  for (int n=n0; n<n0+16; n++){
    const float4* hp = (const float4*)(h_in + n*1024 + lane*16);
    float ha[16];
    *(float4*)(ha+0)=hp[0]; *(float4*)(ha+4)=hp[1]; *(float4*)(ha+8)=hp[2]; *(float4*)(ha+12)=hp[3];
    float s0=0.f, s1=0.f, s2=0.f, s3=0.f;
    if (first){
      #pragma unroll
      for (int i=0;i<16;i++){
        s0 += ha[i]*wh[0][i]; s1 += ha[i]*wh[1][i];
        s2 += ha[i]*wh[2][i]; s3 += ha[i]*wh[3][i];
      }
    } else {
      const float4* xp = (const float4*)(x + n*1024 + lane*16);
      float xa[16];
      *(float4*)(xa+0)=xp[0]; *(float4*)(xa+4)=xp[1]; *(float4*)(xa+8)=xp[2]; *(float4*)(xa+12)=xp[3];
      #pragma unroll
      for (int i=0;i<16;i++){
        s0 += xa[i]*wi[0][i] + ha[i]*wh[0][i];
        s1 += xa[i]*wi[1][i] + ha[i]*wh[1][i];
        s2 += xa[i]*wi[2][i] + ha[i]*wh[2][i];
        s3 += xa[i]*wi[3][i] + ha[i]*wh[3][i];
      }
    }
    #pragma unroll
    for (int o=32;o>0;o>>=1){
      s0 += __shfl_xor(s0, o); s1 += __shfl_xor(s1, o);
      s2 += __shfl_xor(s2, o); s3 += __shfl_xor(s3, o);
    }
    if (lane == 0){
      const int idx = n*1024 + d;
      float gi = sigm(s0 + bias[0]);
      float gf = sigm(s1 + bias[1]);
      float gg = tanh_f(s2 + bias[2]);
      float go = sigm(s3 + bias[3]);
      float cn = gf*c_in[idx] + gi*gg;
      c_out[idx] = cn;
      h_out[idx] = go * tanh_f(cn);
    }
  }
}

// ---------------- q projection: wave-per-2j, n split over 2 blocks --------
__global__ __launch_bounds__(256) void k_q(
    const float* __restrict__ h, const unsigned short* __restrict__ W1,
    const float* __restrict__ b1, float* __restrict__ q)
{
  const int wid = threadIdx.x >> 6, lane = threadIdx.x & 63;
  const int jgrp = blockIdx.x >> 1;
  const int n0 = (blockIdx.x & 1) << 4;
  const int j0 = (jgrp*4 + wid)*2;
  float wf[2][16], bias[2];
  #pragma unroll
  for (int jj=0;jj<2;jj++){
    const long wo = (long)(j0+jj)*1024 + lane*16;
    short8 w0 = *(const short8*)(W1 + wo);
    short8 w1 = *(const short8*)(W1 + wo + 8);
    #pragma unroll
    for (int i=0;i<8;i++){ wf[jj][i] = b2f((unsigned short)w0[i]); wf[jj][i+8] = b2f((unsigned short)w1[i]); }
    bias[jj] = b1[j0+jj];
  }
  for (int n=n0; n<n0+16; n++){
    const float4* hp = (const float4*)(h + n*1024 + lane*16);
    float ha[16];
    *(float4*)(ha+0)=hp[0]; *(float4*)(ha+4)=hp[1]; *(float4*)(ha+8)=hp[2]; *(float4*)(ha+12)=hp[3];
    float s0=0.f, s1=0.f;
    #pragma unroll
    for (int i=0;i<16;i++){ s0 += ha[i]*wf[0][i]; s1 += ha[i]*wf[1][i]; }
    #pragma unroll
    for (int o=32;o>0;o>>=1){ s0 += __shfl_xor(s0, o); s1 += __shfl_xor(s1, o); }
    if (lane == 0){ q[n*AA + j0] = s0 + bias[0]; q[n*AA + j0 + 1] = s1 + bias[1]; }
  }
}

// ---------------- fused attn + softmax(no-max) + x_next partials (fp8) ----
__global__ __launch_bounds__(256) void k_attnx(
    const unsigned char* __restrict__ ep8, const float* __restrict__ qv,
    const float* __restrict__ w3, const float* __restrict__ b3p,
    const int* __restrict__ mask, const unsigned char* __restrict__ enc8,
    float* __restrict__ out, float* __restrict__ part,
    float* __restrict__ psum, int t)
{
  const int n = blockIdx.y, ch = blockIdx.x;
  const int tid = threadIdx.x;
  const int wid = tid >> 6, lane = tid & 63;
  __shared__ float p_s[64];

  float qf[8], w3f[8];
  const float4* qp = (const float4*)(qv + n*AA + lane*8);
  *(float4*)(qf+0) = qp[0]; *(float4*)(qf+4) = qp[1];
  const float4* wp = (const float4*)(w3 + lane*8);
  *(float4*)(w3f+0) = wp[0]; *(float4*)(w3f+4) = wp[1];
  const float b3v = b3p[0];

  #pragma unroll 1
  for (int li = 0; li < 16; li++){
    const int l = ch*64 + wid*16 + li;
    uint2 e = *(const uint2*)(ep8 + ((long)n*LL + l)*AA + lane*8);
    float ef[8];
    ef[0]=DEC8(e.x,0); ef[1]=DEC8(e.x,1); ef[2]=DEC8(e.x,2); ef[3]=DEC8(e.x,3);
    ef[4]=DEC8(e.y,0); ef[5]=DEC8(e.y,1); ef[6]=DEC8(e.y,2); ef[7]=DEC8(e.y,3);
    float s = 0.f;
    #pragma unroll
    for (int i=0;i<8;i++) s += tanh_f(ef[i] + qf[i]) * w3f[i];
    #pragma unroll
    for (int o=32;o>0;o>>=1) s += __shfl_xor(s, o);
    if (lane == 0){
      float a = s + b3v;
      int mk = mask[n*LL + l];
      float aout = a;
      if (!mk) aout += -1e30f;
      out[((long)n*TT + t)*LL + l] = aout;
      p_s[wid*16 + li] = mk ? EXP2(a*LOG2E) : 0.f;
    }
  }
  __syncthreads();

  const unsigned char* base = enc8 + ((long)n*LL + ch*64)*1024 + tid*4;
  float a0=0.f, a1=0.f, a2=0.f, a3=0.f;
  #pragma unroll 4
  for (int li=0; li<64; li++){
    float pv = p_s[li];
    unsigned u = *(const unsigned*)(base + (long)li*1024);
    a0 = fmaf(pv, DEC8(u,0), a0);
    a1 = fmaf(pv, DEC8(u,1), a1);
    a2 = fmaf(pv, DEC8(u,2), a2);
    a3 = fmaf(pv, DEC8(u,3), a3);
  }
  float4 o = {a0,a1,a2,a3};
  *(float4*)(part + ((long)(n*32+ch))*1024 + tid*4) = o;
  if (tid == 0){
    float S = 0.f;
    #pragma unroll
    for (int i=0;i<64;i++) S += p_s[i];
    psum[n*32 + ch] = S;
  }
}

// ---------------- reduce partials -> x (divide by total sum) --------------
__global__ __launch_bounds__(256) void k_xreduce(const float* __restrict__ part,
                                                 const float* __restrict__ psum,
                                                 float* __restrict__ x){
  int idx = blockIdx.x*256 + threadIdx.x;
  int n = idx >> 10, d = idx & 1023;
  float S = 0.f;
  #pragma unroll
  for (int ch=0; ch<32; ch++) S += psum[n*32 + ch];
  float s = 0.f;
  #pragma unroll
  for (int ch=0; ch<32; ch++) s += part[((long)(n*32+ch))*1024 + d];
  x[idx] = s * RCP(S);
}

extern "C" void kernel_launch(void* const* d_in, const int* in_sizes, int n_in,
                              void* d_out, int out_size, void* d_ws, size_t ws_size,
                              hipStream_t stream){
  const float* enc_f = (const float*)d_in[0];
  const float* h0    = (const float*)d_in[1];
  const float* c0    = (const float*)d_in[2];
  const int*   mask  = (const int*)d_in[3];
  const float* Wih_f = (const float*)d_in[4];
  const float* Whh_f = (const float*)d_in[5];
  const float* b_ih  = (const float*)d_in[6];
  const float* b_hh  = (const float*)d_in[7];
  const float* W1_f  = (const float*)d_in[8];
  const float* b1    = (const float*)d_in[9];
  const float* W2_f  = (const float*)d_in[10];
  const float* b2    = (const float*)d_in[11];
  const float* w3    = (const float*)d_in[12];
  const float* b3    = (const float*)d_in[13];
  float* out = (float*)d_out;

  char* ws = (char*)d_ws;
  size_t off = 0;
  auto alloc = [&](size_t bytes){ void* p = ws + off; off += (bytes + 255) & ~255ull; return p; };
  unsigned char*  enc_8 = (unsigned char*)alloc((size_t)NB*LL*DD);     // 64 MB fp8
  unsigned char*  ep_8  = (unsigned char*)alloc((size_t)NB*LL*AA);     // 32 MB fp8
  unsigned short* Wih_b = (unsigned short*)alloc((size_t)4*DD*DD*2);
  unsigned short* Whh_b = (unsigned short*)alloc((size_t)4*DD*DD*2);
  unsigned short* W1_b  = (unsigned short*)alloc((size_t)AA*DD*2);
  unsigned char*  W2_8  = (unsigned char*)alloc((size_t)AA*DD);        // fp8 x32
  float* hA    = (float*)alloc((size_t)NB*DD*4);
  float* hB    = (float*)alloc((size_t)NB*DD*4);
  float* cbuf  = (float*)alloc((size_t)NB*DD*4);
  float* xbuf  = (float*)alloc((size_t)NB*DD*4);
  float* qbuf  = (float*)alloc((size_t)NB*AA*4);
  float* part  = (float*)alloc((size_t)NB*32*DD*4);
  float* psum  = (float*)alloc((size_t)NB*32*4);

  k_cvt_enc<<<4096,256,0,stream>>>(enc_f, enc_8, (long)NB*LL*DD/8);
  k_cvt4<<<4608,256,0,stream>>>(Wih_f, Whh_f, W1_f, W2_f,
                                Wih_b, Whh_b, W1_b, W2_8,
                                (long)4*DD*DD/8, (long)4*DD*DD/8,
                                (long)AA*DD/8, (long)AA*DD/8);
  k_gemm8<<<dim3(512,4),256,0,stream>>>(enc_8, W2_8, b2, ep_8);

  float* hcur = hA; float* hnxt = hB;
  for (int t=0; t<TT; t++){
    k_glstm<<<512,256,0,stream>>>(xbuf,
                                  t==0 ? h0 : hcur,
                                  t==0 ? c0 : cbuf,
                                  Wih_b, Whh_b, b_ih, b_hh,
                                  hnxt, cbuf, t==0 ? 1 : 0);
    k_q<<<128,256,0,stream>>>(hnxt, W1_b, b1, qbuf);
    k_attnx<<<dim3(32,NB),256,0,stream>>>(ep_8, qbuf, w3, b3, mask, enc_8,
                                          out, part, psum, t);
    k_xreduce<<<128,256,0,stream>>>(part, psum, xbuf);
    float* tmp = hcur; hcur = hnxt; hnxt = tmp;
  }
}

// Round 21
// 657.204 us; speedup vs baseline: 2.4575x; 1.0180x over previous
//
#include <hip/hip_runtime.h>

#define NB 32
#define LL 2048
#define DD 1024      // D2
#define AA 512       // ATTN
#define TT 8
#define LOG2E 1.4426950408889634f

typedef short short8 __attribute__((ext_vector_type(8)));
typedef float f32x4 __attribute__((ext_vector_type(4)));

#if __has_builtin(__builtin_amdgcn_exp2f)
#define EXP2(x) __builtin_amdgcn_exp2f(x)
#else
#define EXP2(x) exp2f(x)
#endif
#if __has_builtin(__builtin_amdgcn_rcpf)
#define RCP(x) __builtin_amdgcn_rcpf(x)
#else
#define RCP(x) (1.0f/(x))
#endif

__device__ __forceinline__ unsigned short f2b(float f){
  union { float f; unsigned u; } v; v.f = f;
  unsigned r = v.u + 0x7fffu + ((v.u >> 16) & 1u);
  return (unsigned short)(r >> 16);
}
__device__ __forceinline__ float b2f(unsigned short b){
  union { unsigned u; float f; } v; v.u = ((unsigned)b) << 16;
  return v.f;
}
__device__ __forceinline__ float sigm(float x){
  return RCP(1.f + EXP2(-x * LOG2E));
}
__device__ __forceinline__ float tanh_f(float x){
  return 2.f * RCP(1.f + EXP2(-2.f * LOG2E * x)) - 1.f;
}
__device__ __forceinline__ void gll16(const void* g, void* l){
  __builtin_amdgcn_global_load_lds(
      (const __attribute__((address_space(1))) unsigned int*)(g),
      (__attribute__((address_space(3))) unsigned int*)(l),
      16, 0, 0);
}

// ---- fp8 e4m3 (OCP) encode/decode, HW builtin with SW fallback ----
__device__ __forceinline__ unsigned char sw_enc_e4m3(float f){
  union{float f;unsigned u;} v; v.f = f;
  unsigned s = (v.u>>31)<<7;
  float a = fabsf(f);
  if (a < 0.015625f){
    int q = (int)(a*512.f + 0.5f);
    if (q > 7) return s | (1<<3);
    return s | q;
  }
  int e = ((v.u>>23)&255) - 127;
  unsigned m = ((v.u & 0x7FFFFF) + 0x80000) >> 20;
  if (m == 8){ m = 0; e++; }
  int eb = e + 7;
  if (eb > 15){ eb = 15; m = 6; }
  if (eb <= 0){
    int q = (int)(a*512.f + 0.5f); if (q>7) q=7;
    return s | q;
  }
  return s | (eb<<3) | m;
}
__device__ __forceinline__ unsigned char f2e8(float f){
#if __has_builtin(__builtin_amdgcn_cvt_pk_fp8_f32)
  return (unsigned char)(__builtin_amdgcn_cvt_pk_fp8_f32(f, f, 0, false) & 0xFF);
#else
  return sw_enc_e4m3(f);
#endif
}
__device__ __forceinline__ float sw_dec_e4m3(unsigned char c){
  unsigned s = c>>7, e = (c>>3)&15, m = c&7;
  if (e){ union{unsigned u;float f;} x; x.u = (s<<31)|((e+120)<<23)|(m<<20); return x.f; }
  float r = (float)m * 0.001953125f;
  return s ? -r : r;
}
#if __has_builtin(__builtin_amdgcn_cvt_f32_fp8)
#define DEC8(word, sel) __builtin_amdgcn_cvt_f32_fp8((int)(word), (sel))
#else
#define DEC8(word, sel) sw_dec_e4m3((unsigned char)(((word) >> ((sel)*8)) & 0xFF))
#endif
// decode all 4 bytes of a word into dst[0..3] with LITERAL selectors
#define DEC8X4(dst, word) do { \
    (dst)[0] = DEC8((word), 0); (dst)[1] = DEC8((word), 1); \
    (dst)[2] = DEC8((word), 2); (dst)[3] = DEC8((word), 3); } while(0)

// ---------------- enc cvt: fp32 -> fp8 only ----------------
__global__ __launch_bounds__(256) void k_cvt_enc(const float* __restrict__ in,
                                                 unsigned char* __restrict__ o8,
                                                 long n8){
  long stride = (long)gridDim.x * 256;
  for (long i = (long)blockIdx.x*256 + threadIdx.x; i < n8; i += stride){
    const float4* ip = (const float4*)(in + i*8);
    float4 a = ip[0], b = ip[1];
    uint2 p;
    p.x = (unsigned)f2e8(a.x) | ((unsigned)f2e8(a.y)<<8) |
          ((unsigned)f2e8(a.z)<<16) | ((unsigned)f2e8(a.w)<<24);
    p.y = (unsigned)f2e8(b.x) | ((unsigned)f2e8(b.y)<<8) |
          ((unsigned)f2e8(b.z)<<16) | ((unsigned)f2e8(b.w)<<24);
    *(uint2*)(o8 + i*8) = p;
  }
}

// ------- weight cvts: Wih/Whh -> fp8 x32, W1 -> bf16, W2 -> fp8 x32 -------
__global__ __launch_bounds__(256) void k_cvt4(
    const float* __restrict__ s0, const float* __restrict__ s1,
    const float* __restrict__ s2, const float* __restrict__ s3,
    unsigned char* __restrict__ d0, unsigned char* __restrict__ d1,
    unsigned short* __restrict__ d2, unsigned char* __restrict__ d3,
    long c0, long c1, long c2, long c3)
{
  long i = (long)blockIdx.x*256 + threadIdx.x;
  long idx = i;
  const float* s8 = 0; unsigned char* dd8 = 0;
  if (idx < c0){ s8 = s0; dd8 = d0; }
  else { idx -= c0;
    if (idx < c1){ s8 = s1; dd8 = d1; }
    else { idx -= c1;
      if (idx < c2){
        const float4* ip = (const float4*)(s2 + idx*8);
        float4 a = ip[0], b = ip[1];
        uint4 o;
        o.x = (unsigned)f2b(a.x) | ((unsigned)f2b(a.y) << 16);
        o.y = (unsigned)f2b(a.z) | ((unsigned)f2b(a.w) << 16);
        o.z = (unsigned)f2b(b.x) | ((unsigned)f2b(b.y) << 16);
        o.w = (unsigned)f2b(b.z) | ((unsigned)f2b(b.w) << 16);
        *(uint4*)(d2 + idx*8) = o;
        return;
      }
      idx -= c2; if (idx >= c3) return;
      s8 = s3; dd8 = d3;
    } }
  const float4* ip = (const float4*)(s8 + idx*8);
  float4 a = ip[0], b = ip[1];
  uint2 p;
  p.x = (unsigned)f2e8(a.x*32.f) | ((unsigned)f2e8(a.y*32.f)<<8) |
        ((unsigned)f2e8(a.z*32.f)<<16) | ((unsigned)f2e8(a.w*32.f)<<24);
  p.y = (unsigned)f2e8(b.x*32.f) | ((unsigned)f2e8(b.y*32.f)<<8) |
        ((unsigned)f2e8(b.z*32.f)<<16) | ((unsigned)f2e8(b.w*32.f)<<24);
  *(uint2*)(dd8 + idx*8) = p;
}

// ---------------- enc_proj GEMM, fp8 x fp8, 128x128 tile, XOR swizzle ------
__global__ __launch_bounds__(256) void k_gemm8(
    const unsigned char* __restrict__ A,   // [65536,1024] fp8 enc
    const unsigned char* __restrict__ Bt,  // [512,1024] fp8 (W2*32)
    const float* __restrict__ b2,
    unsigned char* __restrict__ C8)        // [65536,512] fp8 ep
{
  __shared__ unsigned char As[128*64];
  __shared__ unsigned char Bs[128*64];
  const int tid = threadIdx.x;
  const int wid = tid >> 6, lane = tid & 63;
  const int wm = wid >> 1, wn = wid & 1;
  const int hi = lane >> 4, r = lane & 15;
  const long brow = (long)blockIdx.x * 128;
  const int bcol = blockIdx.y * 128;
  const int srow = wid*32 + (lane >> 2);
  const int scol = (((lane & 3) ^ ((lane >> 3) & 3)) << 4);
  const unsigned char* aS0 = A + (brow + srow)*1024 + scol;
  const unsigned char* aS1 = A + (brow + srow + 16)*1024 + scol;
  const unsigned char* bS0 = Bt + (long)(bcol + srow)*1024 + scol;
  const unsigned char* bS1 = Bt + (long)(bcol + srow + 16)*1024 + scol;
  char* aD = (char*)As + wid*2048;
  char* bD = (char*)Bs + wid*2048;

  f32x4 acc[4][4];
  #pragma unroll
  for (int i=0;i<4;i++)
    #pragma unroll
    for (int j=0;j<4;j++) acc[i][j] = (f32x4){0.f,0.f,0.f,0.f};

  const int sw = (r >> 1) & 3;
  const int c0 = hi >> 1;
  const int h8 = (hi & 1) * 8;
  const int p0 = ((c0 ^ sw) << 4) + h8;

  for (int k0 = 0; k0 < 1024; k0 += 64){
    __syncthreads();
    gll16(aS0 + k0, aD);
    gll16(aS1 + k0, aD + 1024);
    gll16(bS0 + k0, bD);
    gll16(bS1 + k0, bD + 1024);
    __syncthreads();
    long af[4][2], bfr[4][2];
    #pragma unroll
    for (int fm=0; fm<4; fm++){
      const char* base = (const char*)As + (wm*64 + fm*16 + r)*64;
      af[fm][0] = *(const long*)(base + p0);
      af[fm][1] = *(const long*)(base + (p0 ^ 32));
    }
    #pragma unroll
    for (int fn=0; fn<4; fn++){
      const char* base = (const char*)Bs + (wn*64 + fn*16 + r)*64;
      bfr[fn][0] = *(const long*)(base + p0);
      bfr[fn][1] = *(const long*)(base + (p0 ^ 32));
    }
    #pragma unroll
    for (int fm=0; fm<4; fm++)
      #pragma unroll
      for (int fn=0; fn<4; fn++){
        acc[fm][fn] = __builtin_amdgcn_mfma_f32_16x16x32_fp8_fp8(af[fm][0], bfr[fn][0], acc[fm][fn], 0, 0, 0);
        acc[fm][fn] = __builtin_amdgcn_mfma_f32_16x16x32_fp8_fp8(af[fm][1], bfr[fn][1], acc[fm][fn], 0, 0, 0);
      }
  }
  const float inv32 = 1.f/32.f;
  #pragma unroll
  for (int fm=0; fm<4; fm++){
    #pragma unroll
    for (int fn=0; fn<4; fn++){
      int col = bcol + wn*64 + fn*16 + r;
      float bias = b2[col];
      #pragma unroll
      for (int q=0; q<4; q++){
        long row = brow + wm*64 + fm*16 + hi*4 + q;
        C8[row*512 + col] = f2e8(acc[fm][fn][q]*inv32 + bias);
      }
    }
  }
}

// ---- fused LSTM: gates (4 rows per wave, same d) + cell; fp8 weights -----
__global__ __launch_bounds__(256) void k_glstm(
    const float* __restrict__ x, const float* __restrict__ h_in,
    const float* __restrict__ c_in,
    const unsigned char* __restrict__ Wih, const unsigned char* __restrict__ Whh,
    const float* __restrict__ b_ih, const float* __restrict__ b_hh,
    float* __restrict__ h_out, float* __restrict__ c_out, int first)
{
  const int wid = threadIdx.x >> 6, lane = threadIdx.x & 63;
  const int d = (blockIdx.x >> 1)*4 + wid;
  const int n0 = (blockIdx.x & 1) << 4;
  float wi[4][16], wh[4][16], bias[4];
  #pragma unroll
  for (int g=0; g<4; g++){
    const int rg = g*1024 + d;
    const long wo = (long)rg*1024 + lane*16;   // fp8: 1 byte/elem
    uint4 vi = *(const uint4*)(Wih + wo);
    uint4 vh = *(const uint4*)(Whh + wo);
    DEC8X4(&wi[g][0],  vi.x); DEC8X4(&wi[g][4],  vi.y);
    DEC8X4(&wi[g][8],  vi.z); DEC8X4(&wi[g][12], vi.w);
    DEC8X4(&wh[g][0],  vh.x); DEC8X4(&wh[g][4],  vh.y);
    DEC8X4(&wh[g][8],  vh.z); DEC8X4(&wh[g][12], vh.w);
    bias[g] = b_ih[rg] + b_hh[rg];
  }
  const float inv32 = 1.f/32.f;
  for (int n=n0; n<n0+16; n++){
    const float4* hp = (const float4*)(h_in + n*1024 + lane*16);
    float ha[16];
    *(float4*)(ha+0)=hp[0]; *(float4*)(ha+4)=hp[1]; *(float4*)(ha+8)=hp[2]; *(float4*)(ha+12)=hp[3];
    float s0=0.f, s1=0.f, s2=0.f, s3=0.f;
    if (first){
      #pragma unroll
      for (int i=0;i<16;i++){
        s0 += ha[i]*wh[0][i]; s1 += ha[i]*wh[1][i];
        s2 += ha[i]*wh[2][i]; s3 += ha[i]*wh[3][i];
      }
    } else {
      const float4* xp = (const float4*)(x + n*1024 + lane*16);
      float xa[16];
      *(float4*)(xa+0)=xp[0]; *(float4*)(xa+4)=xp[1]; *(float4*)(xa+8)=xp[2]; *(float4*)(xa+12)=xp[3];
      #pragma unroll
      for (int i=0;i<16;i++){
        s0 += xa[i]*wi[0][i] + ha[i]*wh[0][i];
        s1 += xa[i]*wi[1][i] + ha[i]*wh[1][i];
        s2 += xa[i]*wi[2][i] + ha[i]*wh[2][i];
        s3 += xa[i]*wi[3][i] + ha[i]*wh[3][i];
      }
    }
    #pragma unroll
    for (int o=32;o>0;o>>=1){
      s0 += __shfl_xor(s0, o); s1 += __shfl_xor(s1, o);
      s2 += __shfl_xor(s2, o); s3 += __shfl_xor(s3, o);
    }
    if (lane == 0){
      const int idx = n*1024 + d;
      float gi = sigm(s0*inv32 + bias[0]);
      float gf = sigm(s1*inv32 + bias[1]);
      float gg = tanh_f(s2*inv32 + bias[2]);
      float go = sigm(s3*inv32 + bias[3]);
      float cn = gf*c_in[idx] + gi*gg;
      c_out[idx] = cn;
      h_out[idx] = go * tanh_f(cn);
    }
  }
}

// ---------------- q projection: wave-per-2j, n split over 2 blocks --------
__global__ __launch_bounds__(256) void k_q(
    const float* __restrict__ h, const unsigned short* __restrict__ W1,
    const float* __restrict__ b1, float* __restrict__ q)
{
  const int wid = threadIdx.x >> 6, lane = threadIdx.x & 63;
  const int jgrp = blockIdx.x >> 1;
  const int n0 = (blockIdx.x & 1) << 4;
  const int j0 = (jgrp*4 + wid)*2;
  float wf[2][16], bias[2];
  #pragma unroll
  for (int jj=0;jj<2;jj++){
    const long wo = (long)(j0+jj)*1024 + lane*16;
    short8 w0 = *(const short8*)(W1 + wo);
    short8 w1 = *(const short8*)(W1 + wo + 8);
    #pragma unroll
    for (int i=0;i<8;i++){ wf[jj][i] = b2f((unsigned short)w0[i]); wf[jj][i+8] = b2f((unsigned short)w1[i]); }
    bias[jj] = b1[j0+jj];
  }
  for (int n=n0; n<n0+16; n++){
    const float4* hp = (const float4*)(h + n*1024 + lane*16);
    float ha[16];
    *(float4*)(ha+0)=hp[0]; *(float4*)(ha+4)=hp[1]; *(float4*)(ha+8)=hp[2]; *(float4*)(ha+12)=hp[3];
    float s0=0.f, s1=0.f;
    #pragma unroll
    for (int i=0;i<16;i++){ s0 += ha[i]*wf[0][i]; s1 += ha[i]*wf[1][i]; }
    #pragma unroll
    for (int o=32;o>0;o>>=1){ s0 += __shfl_xor(s0, o); s1 += __shfl_xor(s1, o); }
    if (lane == 0){ q[n*AA + j0] = s0 + bias[0]; q[n*AA + j0 + 1] = s1 + bias[1]; }
  }
}

// ---------------- fused attn + softmax(no-max) + x_next partials (fp8) ----
__global__ __launch_bounds__(256) void k_attnx(
    const unsigned char* __restrict__ ep8, const float* __restrict__ qv,
    const float* __restrict__ w3, const float* __restrict__ b3p,
    const int* __restrict__ mask, const unsigned char* __restrict__ enc8,
    float* __restrict__ out, float* __restrict__ part,
    float* __restrict__ psum, int t)
{
  const int n = blockIdx.y, ch = blockIdx.x;
  const int tid = threadIdx.x;
  const int wid = tid >> 6, lane = tid & 63;
  __shared__ float p_s[64];

  float qf[8], w3f[8];
  const float4* qp = (const float4*)(qv + n*AA + lane*8);
  *(float4*)(qf+0) = qp[0]; *(float4*)(qf+4) = qp[1];
  const float4* wp = (const float4*)(w3 + lane*8);
  *(float4*)(w3f+0) = wp[0]; *(float4*)(w3f+4) = wp[1];
  const float b3v = b3p[0];

  #pragma unroll 1
  for (int li = 0; li < 16; li++){
    const int l = ch*64 + wid*16 + li;
    uint2 e = *(const uint2*)(ep8 + ((long)n*LL + l)*AA + lane*8);
    float ef[8];
    DEC8X4(&ef[0], e.x); DEC8X4(&ef[4], e.y);
    float s = 0.f;
    #pragma unroll
    for (int i=0;i<8;i++) s += tanh_f(ef[i] + qf[i]) * w3f[i];
    #pragma unroll
    for (int o=32;o>0;o>>=1) s += __shfl_xor(s, o);
    if (lane == 0){
      float a = s + b3v;
      int mk = mask[n*LL + l];
      float aout = a;
      if (!mk) aout += -1e30f;
      out[((long)n*TT + t)*LL + l] = aout;
      p_s[wid*16 + li] = mk ? EXP2(a*LOG2E) : 0.f;
    }
  }
  __syncthreads();

  const unsigned char* base = enc8 + ((long)n*LL + ch*64)*1024 + tid*4;
  float a0=0.f, a1=0.f, a2=0.f, a3=0.f;
  #pragma unroll 4
  for (int li=0; li<64; li++){
    float pv = p_s[li];
    unsigned u = *(const unsigned*)(base + (long)li*1024);
    a0 = fmaf(pv, DEC8(u,0), a0);
    a1 = fmaf(pv, DEC8(u,1), a1);
    a2 = fmaf(pv, DEC8(u,2), a2);
    a3 = fmaf(pv, DEC8(u,3), a3);
  }
  float4 o = {a0,a1,a2,a3};
  *(float4*)(part + ((long)(n*32+ch))*1024 + tid*4) = o;
  if (tid == 0){
    float S = 0.f;
    #pragma unroll
    for (int i=0;i<64;i++) S += p_s[i];
    psum[n*32 + ch] = S;
  }
}

// ---------------- reduce partials -> x (divide by total sum) --------------
__global__ __launch_bounds__(256) void k_xreduce(const float* __restrict__ part,
                                                 const float* __restrict__ psum,
                                                 float* __restrict__ x){
  int idx = blockIdx.x*256 + threadIdx.x;
  int n = idx >> 10, d = idx & 1023;
  float S = 0.f;
  #pragma unroll
  for (int ch=0; ch<32; ch++) S += psum[n*32 + ch];
  float s = 0.f;
  #pragma unroll
  for (int ch=0; ch<32; ch++) s += part[((long)(n*32+ch))*1024 + d];
  x[idx] = s * RCP(S);
}

extern "C" void kernel_launch(void* const* d_in, const int* in_sizes, int n_in,
                              void* d_out, int out_size, void* d_ws, size_t ws_size,
                              hipStream_t stream){
  const float* enc_f = (const float*)d_in[0];
  const float* h0    = (const float*)d_in[1];
  const float* c0    = (const float*)d_in[2];
  const int*   mask  = (const int*)d_in[3];
  const float* Wih_f = (const float*)d_in[4];
  const float* Whh_f = (const float*)d_in[5];
  const float* b_ih  = (const float*)d_in[6];
  const float* b_hh  = (const float*)d_in[7];
  const float* W1_f  = (const float*)d_in[8];
  const float* b1    = (const float*)d_in[9];
  const float* W2_f  = (const float*)d_in[10];
  const float* b2    = (const float*)d_in[11];
  const float* w3    = (const float*)d_in[12];
  const float* b3    = (const float*)d_in[13];
  float* out = (float*)d_out;

  char* ws = (char*)d_ws;
  size_t off = 0;
  auto alloc = [&](size_t bytes){ void* p = ws + off; off += (bytes + 255) & ~255ull; return p; };
  unsigned char*  enc_8 = (unsigned char*)alloc((size_t)NB*LL*DD);     // 64 MB fp8
  unsigned char*  ep_8  = (unsigned char*)alloc((size_t)NB*LL*AA);     // 32 MB fp8
  unsigned char*  Wih_8 = (unsigned char*)alloc((size_t)4*DD*DD);      // 4 MB fp8 x32
  unsigned char*  Whh_8 = (unsigned char*)alloc((size_t)4*DD*DD);      // 4 MB fp8 x32
  unsigned short* W1_b  = (unsigned short*)alloc((size_t)AA*DD*2);
  unsigned char*  W2_8  = (unsigned char*)alloc((size_t)AA*DD);        // fp8 x32
  float* hA    = (float*)alloc((size_t)NB*DD*4);
  float* hB    = (float*)alloc((size_t)NB*DD*4);
  float* cbuf  = (float*)alloc((size_t)NB*DD*4);
  float* xbuf  = (float*)alloc((size_t)NB*DD*4);
  float* qbuf  = (float*)alloc((size_t)NB*AA*4);
  float* part  = (float*)alloc((size_t)NB*32*DD*4);
  float* psum  = (float*)alloc((size_t)NB*32*4);

  k_cvt_enc<<<4096,256,0,stream>>>(enc_f, enc_8, (long)NB*LL*DD/8);
  k_cvt4<<<4608,256,0,stream>>>(Wih_f, Whh_f, W1_f, W2_f,
                                Wih_8, Whh_8, W1_b, W2_8,
                                (long)4*DD*DD/8, (long)4*DD*DD/8,
                                (long)AA*DD/8, (long)AA*DD/8);
  k_gemm8<<<dim3(512,4),256,0,stream>>>(enc_8, W2_8, b2, ep_8);

  float* hcur = hA; float* hnxt = hB;
  for (int t=0; t<TT; t++){
    k_glstm<<<512,256,0,stream>>>(xbuf,
                                  t==0 ? h0 : hcur,
                                  t==0 ? c0 : cbuf,
                                  Wih_8, Whh_8, b_ih, b_hh,
                                  hnxt, cbuf, t==0 ? 1 : 0);
    k_q<<<128,256,0,stream>>>(hnxt, W1_b, b1, qbuf);
    k_attnx<<<dim3(32,NB),256,0,stream>>>(ep_8, qbuf, w3, b3, mask, enc_8,
                                          out, part, psum, t);
    k_xreduce<<<128,256,0,stream>>>(part, psum, xbuf);
    float* tmp = hcur; hcur = hnxt; hnxt = tmp;
  }
}